// Round 4
// baseline (835.639 us; speedup 1.0000x reference)
//
#include <hip/hip_runtime.h>

#define NN 100000
#define NE 1600000
#define M_PAD 100032   // 1563 * 64

#define BSH 7
#define BNODES 128               // nodes per bucket
#define NBUCK 782                // ceil(NN / 128)
#define NBUCKP 784
#define CAP 2560                 // words per bucket region (exp 2048, +11 sigma)
#define ECH 2048                 // edges per chunk
#define NCHK 782                 // ceil(NE / ECH)

typedef _Float16 half8v __attribute__((ext_vector_type(8)));
typedef _Float16 half4v __attribute__((ext_vector_type(4)));
typedef float f32x4 __attribute__((ext_vector_type(4)));

// ---------------- bucket partition (no global atomics) ----------------

// per-chunk LDS histogram over buckets -> histT[bucket][chunk]
__global__ __launch_bounds__(256) void k_count(const int* __restrict__ dst,
                                               int* __restrict__ histT) {
    __shared__ int h[NBUCKP];
    const int t = threadIdx.x;
    for (int b = t; b < NBUCKP; b += 256) h[b] = 0;
    __syncthreads();
    const long long e0 = (long long)blockIdx.x * ECH;
#pragma unroll
    for (int i = 0; i < ECH / 256; i++) {
        long long e = e0 + i * 256 + t;
        if (e < NE) atomicAdd(&h[dst[e] >> BSH], 1);
    }
    __syncthreads();
    for (int b = t; b < NBUCK; b += 256) histT[(long long)b * NCHK + blockIdx.x] = h[b];
}

// per-bucket exclusive scan over chunks (in place), total -> cntb
__global__ __launch_bounds__(256) void k_scanb(int* __restrict__ histT,
                                               int* __restrict__ cntb) {
    __shared__ int s[256];
    const int b = blockIdx.x, t = threadIdx.x;
    int* row = histT + (long long)b * NCHK;
    int v[4];
    int sum = 0;
#pragma unroll
    for (int j = 0; j < 4; j++) {
        int idx = t * 4 + j;
        v[j] = (idx < NCHK) ? row[idx] : 0;
        sum += v[j];
    }
    s[t] = sum;
    __syncthreads();
    for (int off = 1; off < 256; off <<= 1) {
        int u = (t >= off) ? s[t - off] : 0;
        __syncthreads();
        s[t] += u;
        __syncthreads();
    }
    int run = s[t] - sum;  // exclusive over thread chunks
#pragma unroll
    for (int j = 0; j < 4; j++) {
        int idx = t * 4 + j;
        if (idx < NCHK) row[idx] = run;
        run += v[j];
    }
    if (t == 255) cntb[b] = s[255];
}

// scatter packed words (src<<7 | dst_local) into bucket regions.
// LDS cursors seeded from scanned offsets: no global atomics; each chunk's
// writes per bucket are consecutive -> good line locality.
__global__ __launch_bounds__(256) void k_part(const int* __restrict__ src,
                                              const int* __restrict__ dst,
                                              const int* __restrict__ histT,
                                              int* __restrict__ data) {
    __shared__ int curs[NBUCKP];
    const int t = threadIdx.x, blk = blockIdx.x;
    for (int b = t; b < NBUCKP; b += 256)
        curs[b] = b * CAP + ((b < NBUCK) ? histT[(long long)b * NCHK + blk] : 0);
    __syncthreads();
    const long long e0 = (long long)blk * ECH;
#pragma unroll
    for (int i = 0; i < ECH / 256; i++) {
        long long e = e0 + i * 256 + t;
        if (e < NE) {
            int d = dst[e], sv = src[e];
            int b = d >> BSH;
            int p = atomicAdd(&curs[b], 1);
            data[p] = (sv << BSH) | (d & (BNODES - 1));
        }
    }
}

// per-bucket degree histogram -> dinv = rsqrt(deg + 1)
__global__ __launch_bounds__(256) void k_deg(const int* __restrict__ data,
                                             const int* __restrict__ cntb,
                                             float* __restrict__ dinv) {
    __shared__ int c[BNODES];
    const int b = blockIdx.x, t = threadIdx.x;
    if (t < BNODES) c[t] = 0;
    __syncthreads();
    const int cnt = cntb[b];
    const int* wp = data + b * CAP;
    for (int e = t; e < cnt; e += 256) atomicAdd(&c[wp[e] & (BNODES - 1)], 1);
    __syncthreads();
    int node = (b << BSH) + t;
    if (t < BNODES && node < NN) dinv[node] = rsqrtf((float)(c[t] + 1));
}

// ---------------- W -> fp16 B-fragment layout ----------------

template<int N>
__global__ __launch_bounds__(256) void k_wfrag(const float* __restrict__ W,
                                               _Float16* __restrict__ Wf) {
    int idx = blockIdx.x * 256 + threadIdx.x;
    if (idx >= 256 * N) return;
    int j = idx & 7;
    int l = (idx >> 3) & 63;
    int f = idx >> 9;
    int nt = f % (N / 16);
    int kt = f / (N / 16);
    int k = kt * 32 + (l >> 4) * 8 + j;
    int c = nt * 16 + (l & 15);
    Wf[idx] = (_Float16)W[k * N + c];
}

// ---------------- MFMA GEMM ----------------
// Out[M_PAD x N] = act(A[. x 256] @ W[256 x N] + bias). 64 rows/block, 4 waves.
// In-place safe for fp16 paths: each block reads only the 64 rows it writes.

template<int N, bool RELU, bool A_FP32, bool OUT_FP16>
__global__ __launch_bounds__(256) void k_gemm_mfma(const void* __restrict__ Ain,
                                                   const _Float16* __restrict__ Wf,
                                                   const float* __restrict__ bias,
                                                   void* __restrict__ Out,
                                                   const float* __restrict__ dinvp,
                                                   float* __restrict__ hs_out) {
    __shared__ char lds[64 * 512];  // 64 rows x 256 fp16
    const int t = threadIdx.x;
    const int lane = t & 63;
    const int w = t >> 6;
    const long long row0 = (long long)blockIdx.x * 64;

    if (A_FP32) {
        const float4* A4 = reinterpret_cast<const float4*>((const float*)Ain + row0 * 256);
        for (int i = t; i < 4096; i += 256) {
            int r = i >> 6, c4 = i & 63;
            float4 v = make_float4(0.f, 0.f, 0.f, 0.f);
            if (row0 + r < NN) v = A4[i];
            half4v hv;
            hv[0] = (_Float16)v.x; hv[1] = (_Float16)v.y;
            hv[2] = (_Float16)v.z; hv[3] = (_Float16)v.w;
            int bo = (r * 512 + c4 * 8) ^ ((r & 7) << 4);
            *reinterpret_cast<half4v*>(lds + bo) = hv;
        }
    } else {
        const half8v* A8 = reinterpret_cast<const half8v*>((const _Float16*)Ain + row0 * 256);
        for (int i = t; i < 2048; i += 256) {
            int r = i >> 5, c8 = i & 31;
            int bo = (r * 512 + c8 * 16) ^ ((r & 7) << 4);
            *reinterpret_cast<half8v*>(lds + bo) = A8[i];
        }
    }
    __syncthreads();

    constexpr int WMT = (N == 256) ? 4 : 1;
    constexpr int WNT = (N == 256) ? 4 : 2;
    const int rw = (N == 256) ? 0 : w * 16;
    const int cw = (N == 256) ? w * 64 : 0;

    f32x4 acc[WMT][WNT];
#pragma unroll
    for (int mt = 0; mt < WMT; mt++)
#pragma unroll
        for (int nt = 0; nt < WNT; nt++) acc[mt][nt] = (f32x4)0.f;

    const half8v* Wf8 = reinterpret_cast<const half8v*>(Wf);

#pragma unroll
    for (int kt = 0; kt < 8; kt++) {
        half8v a[WMT], b[WNT];
#pragma unroll
        for (int mt = 0; mt < WMT; mt++) {
            int row = rw + mt * 16 + (lane & 15);
            int bo = (row * 512 + kt * 64 + ((lane >> 4) << 4)) ^ ((row & 7) << 4);
            a[mt] = *reinterpret_cast<const half8v*>(lds + bo);
        }
#pragma unroll
        for (int nt = 0; nt < WNT; nt++) {
            int f = kt * (N / 16) + (cw >> 4) + nt;
            b[nt] = Wf8[f * 64 + lane];
        }
#pragma unroll
        for (int mt = 0; mt < WMT; mt++)
#pragma unroll
            for (int nt = 0; nt < WNT; nt++)
                acc[mt][nt] = __builtin_amdgcn_mfma_f32_16x16x32_f16(a[mt], b[nt], acc[mt][nt], 0, 0, 0);
    }

#pragma unroll
    for (int mt = 0; mt < WMT; mt++)
#pragma unroll
        for (int nt = 0; nt < WNT; nt++) {
            int colc = cw + nt * 16 + (lane & 15);
            float bv = bias[colc];
#pragma unroll
            for (int r = 0; r < 4; r++) {
                long long row = row0 + rw + mt * 16 + (lane >> 4) * 4 + r;
                float v = acc[mt][nt][r] + bv;
                if (RELU) v = fmaxf(v, 0.f);
                if (OUT_FP16) {
                    ((_Float16*)Out)[row * N + colc] = (_Float16)v;
                } else {
                    if (row < NN) {
                        ((float*)Out)[row * N + colc] = v;
                        hs_out[row * N + colc] = dinvp[row] * v;  // pre-scaled copy
                    }
                }
            }
        }
}

// ---------------- fused APPNP iteration (bucket LDS aggregation) ----------------
// agg[dl][c] += hs[src][c]  (hs = dinv*h);  then
// hnew = 0.9 * dinv_d * (agg + hs[d]) + 0.1 * h0;  out = FINAL ? hnew : dinv_d*hnew

template<bool FINAL>
__global__ __launch_bounds__(256) void k_agg(const int* __restrict__ data,
                                             const int* __restrict__ cntb,
                                             const float* __restrict__ dinv,
                                             const float* __restrict__ hs,
                                             const float* __restrict__ h0,
                                             float* __restrict__ outp) {
    __shared__ float agg[BNODES][32];  // 16 KB
    const int b = blockIdx.x, t = threadIdx.x;
    for (int i = t; i < BNODES * 32; i += 256) ((float*)agg)[i] = 0.f;
    __syncthreads();
    const int cnt = cntb[b];
    const int* wp = data + b * CAP;
    const int lane = t & 31, grp = t >> 5;  // 8 edge-groups, 32 lanes each
    for (int e = grp; e < cnt; e += 32) {
        int e1 = e + 8, e2 = e + 16, e3 = e + 24;
        int w0 = wp[e];
        int w1 = (e1 < cnt) ? wp[e1] : w0;
        int w2 = (e2 < cnt) ? wp[e2] : w0;
        int w3 = (e3 < cnt) ? wp[e3] : w0;
        float v0 = hs[(size_t)(w0 >> BSH) * 32 + lane];
        float v1 = hs[(size_t)(w1 >> BSH) * 32 + lane];
        float v2 = hs[(size_t)(w2 >> BSH) * 32 + lane];
        float v3 = hs[(size_t)(w3 >> BSH) * 32 + lane];
        atomicAdd(&agg[w0 & (BNODES - 1)][lane], v0);
        if (e1 < cnt) atomicAdd(&agg[w1 & (BNODES - 1)][lane], v1);
        if (e2 < cnt) atomicAdd(&agg[w2 & (BNODES - 1)][lane], v2);
        if (e3 < cnt) atomicAdd(&agg[w3 & (BNODES - 1)][lane], v3);
    }
    __syncthreads();
    for (int i = t; i < BNODES * 32; i += 256) {
        int dl = i >> 5, c = i & 31;
        long long node = ((long long)b << BSH) + dl;
        if (node < NN) {
            float dd = dinv[node];
            size_t off = (size_t)node * 32 + c;
            float hnew = 0.9f * dd * (agg[dl][c] + hs[off]) + 0.1f * h0[off];
            outp[off] = FINAL ? hnew : dd * hnew;
        }
    }
}

// ---------------- launch ----------------

extern "C" void kernel_launch(void* const* d_in, const int* in_sizes, int n_in,
                              void* d_out, int out_size, void* d_ws, size_t ws_size,
                              hipStream_t stream) {
    const float* x     = (const float*)d_in[0];
    const int*   ei    = (const int*)d_in[1];
    const float* W_in  = (const float*)d_in[2];
    const float* b_in  = (const float*)d_in[3];
    const float* W_h   = (const float*)d_in[4];
    const float* b_h   = (const float*)d_in[5];
    const float* W_out = (const float*)d_in[6];
    const float* b_out = (const float*)d_in[7];
    float* out = (float*)d_out;

    const int* srcv = ei;
    const int* dstv = ei + NE;

    char* ws = (char*)d_ws;
    _Float16* h1h  = (_Float16*)ws;                              // M_PAD*256 f16 (51.2MB)
    float* h0      = (float*)(h1h + (size_t)M_PAD * 256);        // NN*32 f32
    float* hs0     = h0 + (size_t)NN * 32;                       // NN*32
    float* hs1     = hs0 + (size_t)NN * 32;                      // NN*32
    float* dinv    = hs1 + (size_t)NN * 32;                      // NN
    _Float16* Wf_in  = (_Float16*)(dinv + NN);                   // 256*256
    _Float16* Wf_h   = Wf_in + 256 * 256;                        // 256*256
    _Float16* Wf_out = Wf_h + 256 * 256;                         // 256*32
    int* histT = (int*)(Wf_out + 256 * 32);                      // NBUCK*NCHK
    int* cntb  = histT + (size_t)NBUCK * NCHK;                   // NBUCKP
    int* data  = cntb + NBUCKP;                                  // NBUCKP*CAP (8MB)

    const int GB = M_PAD / 64;

    // --- bucket partition + degrees ---
    k_count<<<NCHK, 256, 0, stream>>>(dstv, histT);
    k_scanb<<<NBUCK, 256, 0, stream>>>(histT, cntb);
    k_part<<<NCHK, 256, 0, stream>>>(srcv, dstv, histT, data);
    k_deg<<<NBUCK, 256, 0, stream>>>(data, cntb, dinv);

    // --- W fragment conversion ---
    k_wfrag<256><<<(256 * 256 + 255) / 256, 256, 0, stream>>>(W_in, Wf_in);
    k_wfrag<256><<<(256 * 256 + 255) / 256, 256, 0, stream>>>(W_h, Wf_h);
    k_wfrag<32 ><<<(256 * 32 + 255) / 256, 256, 0, stream>>>(W_out, Wf_out);

    // --- MLP (fp16 MFMA); gemm3 also emits hs0 = dinv * h0 ---
    k_gemm_mfma<256, true,  true,  true ><<<GB, 256, 0, stream>>>(x,   Wf_in,  b_in,  h1h, nullptr, nullptr);
    k_gemm_mfma<256, true,  false, true ><<<GB, 256, 0, stream>>>(h1h, Wf_h,   b_h,   h1h, nullptr, nullptr);
    k_gemm_mfma<32,  false, false, false><<<GB, 256, 0, stream>>>(h1h, Wf_out, b_out, h0,  dinv, hs0);

    // --- APPNP: K = 2 ---
    k_agg<false><<<NBUCK, 256, 0, stream>>>(data, cntb, dinv, hs0, h0, hs1);
    k_agg<true ><<<NBUCK, 256, 0, stream>>>(data, cntb, dinv, hs1, h0, out);
}

// Round 5
// 236.318 us; speedup vs baseline: 3.5361x; 3.5361x over previous
//
#include <hip/hip_runtime.h>

#define NN 100000
#define NE 1600000
#define M_PAD 100032   // 1563 * 64

#define BSH 7
#define BNODES 128               // nodes per bucket
#define NBUCK 782                // ceil(NN / 128)
#define NBUCKP 784
#define CAP 2560                 // words per bucket region (exp 2048, +11 sigma)
#define ECH 2048                 // edges per chunk
#define NCHK 782                 // ceil(NE / ECH)

typedef _Float16 half8v __attribute__((ext_vector_type(8)));
typedef _Float16 half4v __attribute__((ext_vector_type(4)));
typedef float f32x4 __attribute__((ext_vector_type(4)));

// ---------------- bucket partition (no global atomics) ----------------

// per-chunk LDS histogram over buckets -> histT[bucket][chunk]
__global__ __launch_bounds__(256) void k_count(const int* __restrict__ dst,
                                               int* __restrict__ histT) {
    __shared__ int h[NBUCKP];
    const int t = threadIdx.x;
    for (int b = t; b < NBUCKP; b += 256) h[b] = 0;
    __syncthreads();
    const long long e0 = (long long)blockIdx.x * ECH;
#pragma unroll
    for (int i = 0; i < ECH / 256; i++) {
        long long e = e0 + i * 256 + t;
        if (e < NE) atomicAdd(&h[dst[e] >> BSH], 1);
    }
    __syncthreads();
    for (int b = t; b < NBUCK; b += 256) histT[(long long)b * NCHK + blockIdx.x] = h[b];
}

// per-bucket exclusive scan over chunks (in place), total -> cntb
__global__ __launch_bounds__(256) void k_scanb(int* __restrict__ histT,
                                               int* __restrict__ cntb) {
    __shared__ int s[256];
    const int b = blockIdx.x, t = threadIdx.x;
    int* row = histT + (long long)b * NCHK;
    int v[4];
    int sum = 0;
#pragma unroll
    for (int j = 0; j < 4; j++) {
        int idx = t * 4 + j;
        v[j] = (idx < NCHK) ? row[idx] : 0;
        sum += v[j];
    }
    s[t] = sum;
    __syncthreads();
    for (int off = 1; off < 256; off <<= 1) {
        int u = (t >= off) ? s[t - off] : 0;
        __syncthreads();
        s[t] += u;
        __syncthreads();
    }
    int run = s[t] - sum;  // exclusive over thread chunks
#pragma unroll
    for (int j = 0; j < 4; j++) {
        int idx = t * 4 + j;
        if (idx < NCHK) row[idx] = run;
        run += v[j];
    }
    if (t == 255) cntb[b] = s[255];
}

// scatter packed words (src<<7 | dst_local) into bucket regions.
__global__ __launch_bounds__(256) void k_part(const int* __restrict__ src,
                                              const int* __restrict__ dst,
                                              const int* __restrict__ histT,
                                              int* __restrict__ data) {
    __shared__ int curs[NBUCKP];
    const int t = threadIdx.x, blk = blockIdx.x;
    for (int b = t; b < NBUCKP; b += 256)
        curs[b] = b * CAP + ((b < NBUCK) ? histT[(long long)b * NCHK + blk] : 0);
    __syncthreads();
    const long long e0 = (long long)blk * ECH;
#pragma unroll
    for (int i = 0; i < ECH / 256; i++) {
        long long e = e0 + i * 256 + t;
        if (e < NE) {
            int d = dst[e], sv = src[e];
            int b = d >> BSH;
            int p = atomicAdd(&curs[b], 1);
            data[p] = (sv << BSH) | (d & (BNODES - 1));
        }
    }
}

// per-bucket LDS counting sort -> full dst-ordered col[] + beg/end + dinv.
__global__ __launch_bounds__(256) void k_sortb(const int* __restrict__ data,
                                               const int* __restrict__ cntb,
                                               int* __restrict__ col,
                                               int* __restrict__ begp,
                                               int* __restrict__ endp,
                                               float* __restrict__ dinv) {
    __shared__ int hist[BNODES];
    __shared__ int scn[BNODES];
    __shared__ int curs[BNODES];
    const int b = blockIdx.x, t = threadIdx.x;
    if (t < BNODES) hist[t] = 0;
    __syncthreads();
    const int cnt = cntb[b];
    const int* wp = data + b * CAP;
    for (int e = t; e < cnt; e += 256) atomicAdd(&hist[wp[e] & (BNODES - 1)], 1);
    __syncthreads();
    if (t < BNODES) scn[t] = hist[t];
    __syncthreads();
    for (int off = 1; off < BNODES; off <<= 1) {
        int v = (t < BNODES && t >= off) ? scn[t - off] : 0;
        __syncthreads();
        if (t < BNODES) scn[t] += v;
        __syncthreads();
    }
    if (t < BNODES) {
        int beg = scn[t] - hist[t];  // exclusive
        curs[t] = beg;
        int node = (b << BSH) + t;
        if (node < NN) {
            begp[node] = b * CAP + beg;
            endp[node] = b * CAP + scn[t];
            dinv[node] = rsqrtf((float)(hist[t] + 1));
        }
    }
    __syncthreads();
    for (int e = t; e < cnt; e += 256) {
        int w = wp[e];
        int p = atomicAdd(&curs[w & (BNODES - 1)], 1);
        col[b * CAP + p] = w >> BSH;
    }
}

// ---------------- W -> fp16 B-fragment layout ----------------

template<int N>
__global__ __launch_bounds__(256) void k_wfrag(const float* __restrict__ W,
                                               _Float16* __restrict__ Wf) {
    int idx = blockIdx.x * 256 + threadIdx.x;
    if (idx >= 256 * N) return;
    int j = idx & 7;
    int l = (idx >> 3) & 63;
    int f = idx >> 9;
    int nt = f % (N / 16);
    int kt = f / (N / 16);
    int k = kt * 32 + (l >> 4) * 8 + j;
    int c = nt * 16 + (l & 15);
    Wf[idx] = (_Float16)W[k * N + c];
}

// ---------------- MFMA GEMM ----------------
// Out[M_PAD x N] = act(A[. x 256] @ W[256 x N] + bias). 64 rows/block, 4 waves.
// In-place safe for fp16 paths: each block reads only the 64 rows it writes.

template<int N, bool RELU, bool A_FP32, bool OUT_FP16>
__global__ __launch_bounds__(256) void k_gemm_mfma(const void* __restrict__ Ain,
                                                   const _Float16* __restrict__ Wf,
                                                   const float* __restrict__ bias,
                                                   void* __restrict__ Out,
                                                   const float* __restrict__ dinvp,
                                                   float* __restrict__ hs_out) {
    __shared__ char lds[64 * 512];  // 64 rows x 256 fp16
    const int t = threadIdx.x;
    const int lane = t & 63;
    const int w = t >> 6;
    const long long row0 = (long long)blockIdx.x * 64;

    if (A_FP32) {
        const float4* A4 = reinterpret_cast<const float4*>((const float*)Ain + row0 * 256);
        for (int i = t; i < 4096; i += 256) {
            int r = i >> 6, c4 = i & 63;
            float4 v = make_float4(0.f, 0.f, 0.f, 0.f);
            if (row0 + r < NN) v = A4[i];
            half4v hv;
            hv[0] = (_Float16)v.x; hv[1] = (_Float16)v.y;
            hv[2] = (_Float16)v.z; hv[3] = (_Float16)v.w;
            int bo = (r * 512 + c4 * 8) ^ ((r & 7) << 4);
            *reinterpret_cast<half4v*>(lds + bo) = hv;
        }
    } else {
        const half8v* A8 = reinterpret_cast<const half8v*>((const _Float16*)Ain + row0 * 256);
        for (int i = t; i < 2048; i += 256) {
            int r = i >> 5, c8 = i & 31;
            int bo = (r * 512 + c8 * 16) ^ ((r & 7) << 4);
            *reinterpret_cast<half8v*>(lds + bo) = A8[i];
        }
    }
    __syncthreads();

    constexpr int WMT = (N == 256) ? 4 : 1;
    constexpr int WNT = (N == 256) ? 4 : 2;
    const int rw = (N == 256) ? 0 : w * 16;
    const int cw = (N == 256) ? w * 64 : 0;

    f32x4 acc[WMT][WNT];
#pragma unroll
    for (int mt = 0; mt < WMT; mt++)
#pragma unroll
        for (int nt = 0; nt < WNT; nt++) acc[mt][nt] = (f32x4)0.f;

    const half8v* Wf8 = reinterpret_cast<const half8v*>(Wf);

#pragma unroll
    for (int kt = 0; kt < 8; kt++) {
        half8v a[WMT], b[WNT];
#pragma unroll
        for (int mt = 0; mt < WMT; mt++) {
            int row = rw + mt * 16 + (lane & 15);
            int bo = (row * 512 + kt * 64 + ((lane >> 4) << 4)) ^ ((row & 7) << 4);
            a[mt] = *reinterpret_cast<const half8v*>(lds + bo);
        }
#pragma unroll
        for (int nt = 0; nt < WNT; nt++) {
            int f = kt * (N / 16) + (cw >> 4) + nt;
            b[nt] = Wf8[f * 64 + lane];
        }
#pragma unroll
        for (int mt = 0; mt < WMT; mt++)
#pragma unroll
            for (int nt = 0; nt < WNT; nt++)
                acc[mt][nt] = __builtin_amdgcn_mfma_f32_16x16x32_f16(a[mt], b[nt], acc[mt][nt], 0, 0, 0);
    }

#pragma unroll
    for (int mt = 0; mt < WMT; mt++)
#pragma unroll
        for (int nt = 0; nt < WNT; nt++) {
            int colc = cw + nt * 16 + (lane & 15);
            float bv = bias[colc];
#pragma unroll
            for (int r = 0; r < 4; r++) {
                long long row = row0 + rw + mt * 16 + (lane >> 4) * 4 + r;
                float v = acc[mt][nt][r] + bv;
                if (RELU) v = fmaxf(v, 0.f);
                if (OUT_FP16) {
                    ((_Float16*)Out)[row * N + colc] = (_Float16)v;
                } else {
                    if (row < NN) {
                        ((float*)Out)[row * N + colc] = v;
                        hs_out[row * N + colc] = dinvp[row] * v;  // pre-scaled copy
                    }
                }
            }
        }
}

// ---------------- fused APPNP step (per-node gather, 4-way unrolled) ----------------
// sum = Σ_src hs[src][c]  (hs = dinv*h);
// hnew = 0.9 * dd * (sum + hs[node]) + 0.1 * h0;  out = FINAL ? hnew : dd*hnew

template<bool FINAL>
__global__ __launch_bounds__(256) void k_appnp(const int* __restrict__ begp,
                                               const int* __restrict__ endp,
                                               const int* __restrict__ col,
                                               const float* __restrict__ dinv,
                                               const float* __restrict__ hs,
                                               const float* __restrict__ h0,
                                               float* __restrict__ outp) {
    int node = blockIdx.x * 8 + (threadIdx.x >> 5);
    if (node >= NN) return;
    int c = threadIdx.x & 31;
    int e = begp[node];
    const int end = endp[node];
    float a0 = 0.f, a1 = 0.f, a2 = 0.f, a3 = 0.f;
    for (; e + 4 <= end; e += 4) {
        int s0 = col[e], s1 = col[e + 1], s2 = col[e + 2], s3 = col[e + 3];
        a0 += hs[(size_t)s0 * 32 + c];
        a1 += hs[(size_t)s1 * 32 + c];
        a2 += hs[(size_t)s2 * 32 + c];
        a3 += hs[(size_t)s3 * 32 + c];
    }
    for (; e < end; e++) a0 += hs[(size_t)col[e] * 32 + c];
    size_t off = (size_t)node * 32 + c;
    float dd = dinv[node];
    float hnew = 0.9f * dd * (((a0 + a1) + (a2 + a3)) + hs[off]) + 0.1f * h0[off];
    outp[off] = FINAL ? hnew : dd * hnew;
}

// ---------------- launch ----------------

extern "C" void kernel_launch(void* const* d_in, const int* in_sizes, int n_in,
                              void* d_out, int out_size, void* d_ws, size_t ws_size,
                              hipStream_t stream) {
    const float* x     = (const float*)d_in[0];
    const int*   ei    = (const int*)d_in[1];
    const float* W_in  = (const float*)d_in[2];
    const float* b_in  = (const float*)d_in[3];
    const float* W_h   = (const float*)d_in[4];
    const float* b_h   = (const float*)d_in[5];
    const float* W_out = (const float*)d_in[6];
    const float* b_out = (const float*)d_in[7];
    float* out = (float*)d_out;

    const int* srcv = ei;
    const int* dstv = ei + NE;

    char* ws = (char*)d_ws;
    _Float16* h1h  = (_Float16*)ws;                              // M_PAD*256 f16 (51.2MB)
    float* h0      = (float*)(h1h + (size_t)M_PAD * 256);        // NN*32 f32
    float* hs0     = h0 + (size_t)NN * 32;                       // NN*32
    float* hs1     = hs0 + (size_t)NN * 32;                      // NN*32
    float* dinv    = hs1 + (size_t)NN * 32;                      // NN
    _Float16* Wf_in  = (_Float16*)(dinv + NN);                   // 256*256
    _Float16* Wf_h   = Wf_in + 256 * 256;                        // 256*256
    _Float16* Wf_out = Wf_h + 256 * 256;                         // 256*32
    int* histT = (int*)(Wf_out + 256 * 32);                      // NBUCK*NCHK (2.4MB)
    int* cntb  = histT + (size_t)NBUCK * NCHK;                   // NBUCKP
    int* data  = cntb + NBUCKP;                                  // NBUCKP*CAP (8MB)
    int* col   = data + (size_t)NBUCKP * CAP;                    // NBUCKP*CAP (8MB)
    int* begp  = col + (size_t)NBUCKP * CAP;                     // NN
    int* endp  = begp + NN;                                      // NN

    const int GB = M_PAD / 64;

    // --- bucket partition + local counting sort -> CSR + dinv ---
    k_count<<<NCHK, 256, 0, stream>>>(dstv, histT);
    k_scanb<<<NBUCK, 256, 0, stream>>>(histT, cntb);
    k_part<<<NCHK, 256, 0, stream>>>(srcv, dstv, histT, data);
    k_sortb<<<NBUCK, 256, 0, stream>>>(data, cntb, col, begp, endp, dinv);

    // --- W fragment conversion ---
    k_wfrag<256><<<(256 * 256 + 255) / 256, 256, 0, stream>>>(W_in, Wf_in);
    k_wfrag<256><<<(256 * 256 + 255) / 256, 256, 0, stream>>>(W_h, Wf_h);
    k_wfrag<32 ><<<(256 * 32 + 255) / 256, 256, 0, stream>>>(W_out, Wf_out);

    // --- MLP (fp16 MFMA); gemm3 also emits hs0 = dinv * h0 ---
    k_gemm_mfma<256, true,  true,  true ><<<GB, 256, 0, stream>>>(x,   Wf_in,  b_in,  h1h, nullptr, nullptr);
    k_gemm_mfma<256, true,  false, true ><<<GB, 256, 0, stream>>>(h1h, Wf_h,   b_h,   h1h, nullptr, nullptr);
    k_gemm_mfma<32,  false, false, false><<<GB, 256, 0, stream>>>(h1h, Wf_out, b_out, h0,  dinv, hs0);

    // --- APPNP: K = 2 ---
    k_appnp<false><<<(NN + 7) / 8, 256, 0, stream>>>(begp, endp, col, dinv, hs0, h0, hs1);
    k_appnp<true ><<<(NN + 7) / 8, 256, 0, stream>>>(begp, endp, col, dinv, hs1, h0, out);
}

// Round 6
// 215.593 us; speedup vs baseline: 3.8760x; 1.0961x over previous
//
#include <hip/hip_runtime.h>

#define NN 100000
#define NE 1600000
#define M_PAD 100032   // 1563 * 64

#define BSH 7
#define BNODES 128               // nodes per bucket
#define NBUCK 782                // ceil(NN / 128)
#define NBUCKP 784
#define CAP 2560                 // words per bucket region (exp 2048, +11 sigma)
#define ECH 2048                 // edges per chunk
#define NCHK 782                 // ceil(NE / ECH)

typedef _Float16 half8v __attribute__((ext_vector_type(8)));
typedef _Float16 half4v __attribute__((ext_vector_type(4)));
typedef float f32x4 __attribute__((ext_vector_type(4)));

// ---------------- bucket partition (no global atomics) ----------------

__global__ __launch_bounds__(256) void k_count(const int* __restrict__ dst,
                                               int* __restrict__ histT) {
    __shared__ int h[NBUCKP];
    const int t = threadIdx.x;
    for (int b = t; b < NBUCKP; b += 256) h[b] = 0;
    __syncthreads();
    const long long e0 = (long long)blockIdx.x * ECH;
#pragma unroll
    for (int i = 0; i < ECH / 256; i++) {
        long long e = e0 + i * 256 + t;
        if (e < NE) atomicAdd(&h[dst[e] >> BSH], 1);
    }
    __syncthreads();
    for (int b = t; b < NBUCK; b += 256) histT[(long long)b * NCHK + blockIdx.x] = h[b];
}

__global__ __launch_bounds__(256) void k_scanb(int* __restrict__ histT,
                                               int* __restrict__ cntb) {
    __shared__ int s[256];
    const int b = blockIdx.x, t = threadIdx.x;
    int* row = histT + (long long)b * NCHK;
    int v[4];
    int sum = 0;
#pragma unroll
    for (int j = 0; j < 4; j++) {
        int idx = t * 4 + j;
        v[j] = (idx < NCHK) ? row[idx] : 0;
        sum += v[j];
    }
    s[t] = sum;
    __syncthreads();
    for (int off = 1; off < 256; off <<= 1) {
        int u = (t >= off) ? s[t - off] : 0;
        __syncthreads();
        s[t] += u;
        __syncthreads();
    }
    int run = s[t] - sum;
#pragma unroll
    for (int j = 0; j < 4; j++) {
        int idx = t * 4 + j;
        if (idx < NCHK) row[idx] = run;
        run += v[j];
    }
    if (t == 255) cntb[b] = s[255];
}

__global__ __launch_bounds__(256) void k_part(const int* __restrict__ src,
                                              const int* __restrict__ dst,
                                              const int* __restrict__ histT,
                                              int* __restrict__ data) {
    __shared__ int curs[NBUCKP];
    const int t = threadIdx.x, blk = blockIdx.x;
    for (int b = t; b < NBUCKP; b += 256)
        curs[b] = b * CAP + ((b < NBUCK) ? histT[(long long)b * NCHK + blk] : 0);
    __syncthreads();
    const long long e0 = (long long)blk * ECH;
#pragma unroll
    for (int i = 0; i < ECH / 256; i++) {
        long long e = e0 + i * 256 + t;
        if (e < NE) {
            int d = dst[e], sv = src[e];
            int b = d >> BSH;
            int p = atomicAdd(&curs[b], 1);
            data[p] = (sv << BSH) | (d & (BNODES - 1));
        }
    }
}

// per-bucket LDS counting sort -> dst-ordered col[] + beg/end + dinv.
__global__ __launch_bounds__(256) void k_sortb(const int* __restrict__ data,
                                               const int* __restrict__ cntb,
                                               int* __restrict__ col,
                                               int* __restrict__ begp,
                                               int* __restrict__ endp,
                                               float* __restrict__ dinv) {
    __shared__ int hist[BNODES];
    __shared__ int scn[BNODES];
    __shared__ int curs[BNODES];
    const int b = blockIdx.x, t = threadIdx.x;
    if (t < BNODES) hist[t] = 0;
    __syncthreads();
    const int cnt = cntb[b];
    const int* wp = data + b * CAP;
    for (int e = t; e < cnt; e += 256) atomicAdd(&hist[wp[e] & (BNODES - 1)], 1);
    __syncthreads();
    if (t < BNODES) scn[t] = hist[t];
    __syncthreads();
    for (int off = 1; off < BNODES; off <<= 1) {
        int v = (t < BNODES && t >= off) ? scn[t - off] : 0;
        __syncthreads();
        if (t < BNODES) scn[t] += v;
        __syncthreads();
    }
    if (t < BNODES) {
        int beg = scn[t] - hist[t];
        curs[t] = beg;
        int node = (b << BSH) + t;
        if (node < NN) {
            begp[node] = b * CAP + beg;
            endp[node] = b * CAP + scn[t];
            dinv[node] = rsqrtf((float)(hist[t] + 1));
        }
    }
    __syncthreads();
    for (int e = t; e < cnt; e += 256) {
        int w = wp[e];
        int p = atomicAdd(&curs[w & (BNODES - 1)], 1);
        col[b * CAP + p] = w >> BSH;
    }
}

// ---------------- W -> fp16 B-fragment layout (all three, one launch) ----------------
// Wf[((kt*(N/16)+nt)*64 + l)*8 + j] = W[(kt*32 + (l>>4)*8 + j)*N + nt*16 + (l&15)]

__device__ __forceinline__ void wfrag_one(const float* __restrict__ W,
                                          _Float16* __restrict__ Wf, int idx, int N) {
    int j = idx & 7;
    int l = (idx >> 3) & 63;
    int f = idx >> 9;
    int nt = f % (N / 16);
    int kt = f / (N / 16);
    int k = kt * 32 + (l >> 4) * 8 + j;
    int c = nt * 16 + (l & 15);
    Wf[idx] = (_Float16)W[k * N + c];
}

__global__ __launch_bounds__(256) void k_wfrag_all(const float* __restrict__ W1,
                                                   const float* __restrict__ W2,
                                                   const float* __restrict__ W3,
                                                   _Float16* __restrict__ Wf1,
                                                   _Float16* __restrict__ Wf2,
                                                   _Float16* __restrict__ Wf3) {
    int idx = blockIdx.x * 256 + threadIdx.x;
    if (idx < 65536) wfrag_one(W1, Wf1, idx, 256);
    else if (idx < 131072) wfrag_one(W2, Wf2, idx - 65536, 256);
    else if (idx < 139264) wfrag_one(W3, Wf3, idx - 131072, 32);
}

// ---------------- fused MLP: x -> h0, hs0 in ONE kernel ----------------
// 64 rows/block, 4 waves. Activations ping-pong between two 32KB LDS tiles.

__device__ __forceinline__ void gemm256_lds(const char* __restrict__ src,
                                            char* __restrict__ dst,
                                            const half8v* __restrict__ Wf8,
                                            const float* __restrict__ bias,
                                            int lane, int w) {
    f32x4 acc[4][4];
#pragma unroll
    for (int mt = 0; mt < 4; mt++)
#pragma unroll
        for (int nt = 0; nt < 4; nt++) acc[mt][nt] = (f32x4)0.f;

#pragma unroll
    for (int kt = 0; kt < 8; kt++) {
        half8v a[4], b[4];
#pragma unroll
        for (int mt = 0; mt < 4; mt++) {
            int row = mt * 16 + (lane & 15);
            int bo = (row * 512 + kt * 64 + ((lane >> 4) << 4)) ^ ((row & 7) << 4);
            a[mt] = *reinterpret_cast<const half8v*>(src + bo);
        }
#pragma unroll
        for (int nt = 0; nt < 4; nt++) b[nt] = Wf8[(kt * 16 + w * 4 + nt) * 64 + lane];
#pragma unroll
        for (int mt = 0; mt < 4; mt++)
#pragma unroll
            for (int nt = 0; nt < 4; nt++)
                acc[mt][nt] = __builtin_amdgcn_mfma_f32_16x16x32_f16(a[mt], b[nt], acc[mt][nt], 0, 0, 0);
    }

    // epilogue: bias + relu + fp16 -> dst LDS (swizzled)
#pragma unroll
    for (int mt = 0; mt < 4; mt++)
#pragma unroll
        for (int nt = 0; nt < 4; nt++) {
            int colc = w * 64 + nt * 16 + (lane & 15);
            float bv = bias[colc];
#pragma unroll
            for (int r = 0; r < 4; r++) {
                int row = mt * 16 + (lane >> 4) * 4 + r;
                float v = fmaxf(acc[mt][nt][r] + bv, 0.f);
                int bo = (row * 512 + colc * 2) ^ ((row & 7) << 4);
                *reinterpret_cast<_Float16*>(dst + bo) = (_Float16)v;
            }
        }
}

__global__ __launch_bounds__(256) void k_mlp(const float* __restrict__ x,
                                             const _Float16* __restrict__ Wf1,
                                             const _Float16* __restrict__ Wf2,
                                             const _Float16* __restrict__ Wf3,
                                             const float* __restrict__ b1,
                                             const float* __restrict__ b2,
                                             const float* __restrict__ b3,
                                             const float* __restrict__ dinv,
                                             float* __restrict__ h0,
                                             float* __restrict__ hs0) {
    __shared__ char ldsA[64 * 512];
    __shared__ char ldsB[64 * 512];
    const int t = threadIdx.x;
    const int lane = t & 63;
    const int w = t >> 6;
    const long long row0 = (long long)blockIdx.x * 64;

    // stage x tile (fp32 -> fp16, swizzled)
    {
        const float4* A4 = reinterpret_cast<const float4*>(x + row0 * 256);
        for (int i = t; i < 4096; i += 256) {
            int r = i >> 6, c4 = i & 63;
            float4 v = make_float4(0.f, 0.f, 0.f, 0.f);
            if (row0 + r < NN) v = A4[i];
            half4v hv;
            hv[0] = (_Float16)v.x; hv[1] = (_Float16)v.y;
            hv[2] = (_Float16)v.z; hv[3] = (_Float16)v.w;
            int bo = (r * 512 + c4 * 8) ^ ((r & 7) << 4);
            *reinterpret_cast<half4v*>(ldsA + bo) = hv;
        }
    }
    __syncthreads();

    gemm256_lds(ldsA, ldsB, reinterpret_cast<const half8v*>(Wf1), b1, lane, w);  // h1 -> ldsB
    __syncthreads();
    gemm256_lds(ldsB, ldsA, reinterpret_cast<const half8v*>(Wf2), b2, lane, w);  // h2 -> ldsA
    __syncthreads();

    // GEMM3: 64x256 @ 256x32; wave w owns rows [w*16, w*16+16)
    const half8v* Wf38 = reinterpret_cast<const half8v*>(Wf3);
    const int rw = w * 16;
    f32x4 acc[2];
    acc[0] = (f32x4)0.f; acc[1] = (f32x4)0.f;
#pragma unroll
    for (int kt = 0; kt < 8; kt++) {
        int row = rw + (lane & 15);
        int bo = (row * 512 + kt * 64 + ((lane >> 4) << 4)) ^ ((row & 7) << 4);
        half8v a = *reinterpret_cast<const half8v*>(ldsA + bo);
#pragma unroll
        for (int nt = 0; nt < 2; nt++) {
            half8v b = Wf38[(kt * 2 + nt) * 64 + lane];
            acc[nt] = __builtin_amdgcn_mfma_f32_16x16x32_f16(a, b, acc[nt], 0, 0, 0);
        }
    }
#pragma unroll
    for (int nt = 0; nt < 2; nt++) {
        int colc = nt * 16 + (lane & 15);
        float bv = b3[colc];
#pragma unroll
        for (int r = 0; r < 4; r++) {
            long long row = row0 + rw + (lane >> 4) * 4 + r;
            if (row < NN) {
                float v = acc[nt][r] + bv;
                h0[row * 32 + colc] = v;
                hs0[row * 32 + colc] = dinv[row] * v;
            }
        }
    }
}

// ---------------- fused APPNP step (per-node gather, 4-way unrolled) ----------------

template<bool FINAL>
__global__ __launch_bounds__(256) void k_appnp(const int* __restrict__ begp,
                                               const int* __restrict__ endp,
                                               const int* __restrict__ col,
                                               const float* __restrict__ dinv,
                                               const float* __restrict__ hs,
                                               const float* __restrict__ h0,
                                               float* __restrict__ outp) {
    int node = blockIdx.x * 8 + (threadIdx.x >> 5);
    if (node >= NN) return;
    int c = threadIdx.x & 31;
    int e = begp[node];
    const int end = endp[node];
    float a0 = 0.f, a1 = 0.f, a2 = 0.f, a3 = 0.f;
    for (; e + 4 <= end; e += 4) {
        int s0 = col[e], s1 = col[e + 1], s2 = col[e + 2], s3 = col[e + 3];
        a0 += hs[(size_t)s0 * 32 + c];
        a1 += hs[(size_t)s1 * 32 + c];
        a2 += hs[(size_t)s2 * 32 + c];
        a3 += hs[(size_t)s3 * 32 + c];
    }
    for (; e < end; e++) a0 += hs[(size_t)col[e] * 32 + c];
    size_t off = (size_t)node * 32 + c;
    float dd = dinv[node];
    float hnew = 0.9f * dd * (((a0 + a1) + (a2 + a3)) + hs[off]) + 0.1f * h0[off];
    outp[off] = FINAL ? hnew : dd * hnew;
}

// ---------------- launch ----------------

extern "C" void kernel_launch(void* const* d_in, const int* in_sizes, int n_in,
                              void* d_out, int out_size, void* d_ws, size_t ws_size,
                              hipStream_t stream) {
    const float* x     = (const float*)d_in[0];
    const int*   ei    = (const int*)d_in[1];
    const float* W_in  = (const float*)d_in[2];
    const float* b_in  = (const float*)d_in[3];
    const float* W_h   = (const float*)d_in[4];
    const float* b_h   = (const float*)d_in[5];
    const float* W_out = (const float*)d_in[6];
    const float* b_out = (const float*)d_in[7];
    float* out = (float*)d_out;

    const int* srcv = ei;
    const int* dstv = ei + NE;

    char* ws = (char*)d_ws;
    float* h0      = (float*)ws;                                 // NN*32 f32
    float* hs0     = h0 + (size_t)NN * 32;                       // NN*32
    float* hs1     = hs0 + (size_t)NN * 32;                      // NN*32
    float* dinv    = hs1 + (size_t)NN * 32;                      // NN
    _Float16* Wf_in  = (_Float16*)(dinv + NN);                   // 256*256
    _Float16* Wf_h   = Wf_in + 256 * 256;                        // 256*256
    _Float16* Wf_out = Wf_h + 256 * 256;                         // 256*32
    int* histT = (int*)(Wf_out + 256 * 32);                      // NBUCK*NCHK
    int* cntb  = histT + (size_t)NBUCK * NCHK;                   // NBUCKP
    int* data  = cntb + NBUCKP;                                  // NBUCKP*CAP
    int* col   = data + (size_t)NBUCKP * CAP;                    // NBUCKP*CAP
    int* begp  = col + (size_t)NBUCKP * CAP;                     // NN
    int* endp  = begp + NN;                                      // NN

    // --- bucket partition + local counting sort -> CSR + dinv ---
    k_count<<<NCHK, 256, 0, stream>>>(dstv, histT);
    k_scanb<<<NBUCK, 256, 0, stream>>>(histT, cntb);
    k_part<<<NCHK, 256, 0, stream>>>(srcv, dstv, histT, data);
    k_sortb<<<NBUCK, 256, 0, stream>>>(data, cntb, col, begp, endp, dinv);

    // --- W fragments (one launch) ---
    k_wfrag_all<<<544, 256, 0, stream>>>(W_in, W_h, W_out, Wf_in, Wf_h, Wf_out);

    // --- fused MLP (x -> h0, hs0) ---
    k_mlp<<<M_PAD / 64, 256, 0, stream>>>(x, Wf_in, Wf_h, Wf_out, b_in, b_h, b_out,
                                          dinv, h0, hs0);

    // --- APPNP: K = 2 ---
    k_appnp<false><<<(NN + 7) / 8, 256, 0, stream>>>(begp, endp, col, dinv, hs0, h0, hs1);
    k_appnp<true ><<<(NN + 7) / 8, 256, 0, stream>>>(begp, endp, col, dinv, hs1, h0, out);
}

// Round 7
// 197.833 us; speedup vs baseline: 4.2240x; 1.0898x over previous
//
#include <hip/hip_runtime.h>

#define NN 100000
#define NE 1600000

#define BSH 7
#define BNODES 128               // nodes per bucket
#define NBUCK 782                // ceil(NN / 128)
#define NBUCKP 784
#define CAP 2560                 // words per bucket region (exp 2048, +11 sigma)
#define ECH 2048                 // edges per chunk
#define NCHK 782                 // ceil(NE / ECH)

typedef _Float16 half8v __attribute__((ext_vector_type(8)));
typedef _Float16 half4v __attribute__((ext_vector_type(4)));
typedef float f32x4 __attribute__((ext_vector_type(4)));

// ---------------- bucket partition (no global atomics) ----------------

__global__ __launch_bounds__(256) void k_count(const int* __restrict__ dst,
                                               int* __restrict__ histT) {
    __shared__ int h[NBUCKP];
    const int t = threadIdx.x;
    for (int b = t; b < NBUCKP; b += 256) h[b] = 0;
    __syncthreads();
    const long long e0 = (long long)blockIdx.x * ECH;
#pragma unroll
    for (int i = 0; i < ECH / 256; i++) {
        long long e = e0 + i * 256 + t;
        if (e < NE) atomicAdd(&h[dst[e] >> BSH], 1);
    }
    __syncthreads();
    for (int b = t; b < NBUCK; b += 256) histT[(long long)b * NCHK + blockIdx.x] = h[b];
}

__global__ __launch_bounds__(256) void k_scanb(int* __restrict__ histT,
                                               int* __restrict__ cntb) {
    __shared__ int s[256];
    const int b = blockIdx.x, t = threadIdx.x;
    int* row = histT + (long long)b * NCHK;
    int v[4];
    int sum = 0;
#pragma unroll
    for (int j = 0; j < 4; j++) {
        int idx = t * 4 + j;
        v[j] = (idx < NCHK) ? row[idx] : 0;
        sum += v[j];
    }
    s[t] = sum;
    __syncthreads();
    for (int off = 1; off < 256; off <<= 1) {
        int u = (t >= off) ? s[t - off] : 0;
        __syncthreads();
        s[t] += u;
        __syncthreads();
    }
    int run = s[t] - sum;
#pragma unroll
    for (int j = 0; j < 4; j++) {
        int idx = t * 4 + j;
        if (idx < NCHK) row[idx] = run;
        run += v[j];
    }
    if (t == 255) cntb[b] = s[255];
}

__global__ __launch_bounds__(256) void k_part(const int* __restrict__ src,
                                              const int* __restrict__ dst,
                                              const int* __restrict__ histT,
                                              int* __restrict__ data) {
    __shared__ int curs[NBUCKP];
    const int t = threadIdx.x, blk = blockIdx.x;
    for (int b = t; b < NBUCKP; b += 256)
        curs[b] = b * CAP + ((b < NBUCK) ? histT[(long long)b * NCHK + blk] : 0);
    __syncthreads();
    const long long e0 = (long long)blk * ECH;
#pragma unroll
    for (int i = 0; i < ECH / 256; i++) {
        long long e = e0 + i * 256 + t;
        if (e < NE) {
            int d = dst[e], sv = src[e];
            int b = d >> BSH;
            int p = atomicAdd(&curs[b], 1);
            data[p] = (sv << BSH) | (d & (BNODES - 1));
        }
    }
}

// per-bucket LDS counting sort -> dst-ordered col[] + beg/end + dinv.
__global__ __launch_bounds__(256) void k_sortb(const int* __restrict__ data,
                                               const int* __restrict__ cntb,
                                               int* __restrict__ col,
                                               int* __restrict__ begp,
                                               int* __restrict__ endp,
                                               float* __restrict__ dinv) {
    __shared__ int hist[BNODES];
    __shared__ int scn[BNODES];
    __shared__ int curs[BNODES];
    const int b = blockIdx.x, t = threadIdx.x;
    if (t < BNODES) hist[t] = 0;
    __syncthreads();
    const int cnt = cntb[b];
    const int* wp = data + b * CAP;
    for (int e = t; e < cnt; e += 256) atomicAdd(&hist[wp[e] & (BNODES - 1)], 1);
    __syncthreads();
    if (t < BNODES) scn[t] = hist[t];
    __syncthreads();
    for (int off = 1; off < BNODES; off <<= 1) {
        int v = (t < BNODES && t >= off) ? scn[t - off] : 0;
        __syncthreads();
        if (t < BNODES) scn[t] += v;
        __syncthreads();
    }
    if (t < BNODES) {
        int beg = scn[t] - hist[t];
        curs[t] = beg;
        int node = (b << BSH) + t;
        if (node < NN) {
            begp[node] = b * CAP + beg;
            endp[node] = b * CAP + scn[t];
            dinv[node] = rsqrtf((float)(hist[t] + 1));
        }
    }
    __syncthreads();
    for (int e = t; e < cnt; e += 256) {
        int w = wp[e];
        int p = atomicAdd(&curs[w & (BNODES - 1)], 1);
        col[b * CAP + p] = w >> BSH;
    }
}

// ---------------- W -> fp16 B-fragment layout (all three, one launch) ----------------
// Wf[((kt*(N/16)+nt)*64 + l)*8 + j] = W[(kt*32 + (l>>4)*8 + j)*N + nt*16 + (l&15)]

__device__ __forceinline__ void wfrag_one(const float* __restrict__ W,
                                          _Float16* __restrict__ Wf, int idx, int N) {
    int j = idx & 7;
    int l = (idx >> 3) & 63;
    int f = idx >> 9;
    int nt = f % (N / 16);
    int kt = f / (N / 16);
    int k = kt * 32 + (l >> 4) * 8 + j;
    int c = nt * 16 + (l & 15);
    Wf[idx] = (_Float16)W[k * N + c];
}

__global__ __launch_bounds__(256) void k_wfrag_all(const float* __restrict__ W1,
                                                   const float* __restrict__ W2,
                                                   const float* __restrict__ W3,
                                                   _Float16* __restrict__ Wf1,
                                                   _Float16* __restrict__ Wf2,
                                                   _Float16* __restrict__ Wf3) {
    int idx = blockIdx.x * 256 + threadIdx.x;
    if (idx < 65536) wfrag_one(W1, Wf1, idx, 256);
    else if (idx < 131072) wfrag_one(W2, Wf2, idx - 65536, 256);
    else if (idx < 139264) wfrag_one(W3, Wf3, idx - 131072, 32);
}

// ---------------- fused MLP: x -> h0, hs0 in ONE kernel ----------------
// 32 rows/block (NN = 32*3125 exactly), 4 waves, 2x16KB LDS ping-pong.

__device__ __forceinline__ void gemm256_lds32(const char* __restrict__ src,
                                              char* __restrict__ dst,
                                              const half8v* __restrict__ Wf8,
                                              const float* __restrict__ bias,
                                              int lane, int w) {
    f32x4 acc[2][4];
#pragma unroll
    for (int mt = 0; mt < 2; mt++)
#pragma unroll
        for (int nt = 0; nt < 4; nt++) acc[mt][nt] = (f32x4)0.f;

#pragma unroll
    for (int kt = 0; kt < 8; kt++) {
        half8v a[2], b[4];
#pragma unroll
        for (int mt = 0; mt < 2; mt++) {
            int row = mt * 16 + (lane & 15);
            int bo = (row * 512 + kt * 64 + ((lane >> 4) << 4)) ^ ((row & 7) << 4);
            a[mt] = *reinterpret_cast<const half8v*>(src + bo);
        }
#pragma unroll
        for (int nt = 0; nt < 4; nt++) b[nt] = Wf8[(kt * 16 + w * 4 + nt) * 64 + lane];
#pragma unroll
        for (int mt = 0; mt < 2; mt++)
#pragma unroll
            for (int nt = 0; nt < 4; nt++)
                acc[mt][nt] = __builtin_amdgcn_mfma_f32_16x16x32_f16(a[mt], b[nt], acc[mt][nt], 0, 0, 0);
    }

    // epilogue: bias + relu + fp16 -> dst LDS (swizzled)
#pragma unroll
    for (int mt = 0; mt < 2; mt++)
#pragma unroll
        for (int nt = 0; nt < 4; nt++) {
            int colc = w * 64 + nt * 16 + (lane & 15);
            float bv = bias[colc];
#pragma unroll
            for (int r = 0; r < 4; r++) {
                int row = mt * 16 + (lane >> 4) * 4 + r;
                float v = fmaxf(acc[mt][nt][r] + bv, 0.f);
                int bo = (row * 512 + colc * 2) ^ ((row & 7) << 4);
                *reinterpret_cast<_Float16*>(dst + bo) = (_Float16)v;
            }
        }
}

__global__ __launch_bounds__(256, 4) void k_mlp(const float* __restrict__ x,
                                                const _Float16* __restrict__ Wf1,
                                                const _Float16* __restrict__ Wf2,
                                                const _Float16* __restrict__ Wf3,
                                                const float* __restrict__ b1,
                                                const float* __restrict__ b2,
                                                const float* __restrict__ b3,
                                                const float* __restrict__ dinv,
                                                float* __restrict__ h0,
                                                float* __restrict__ hs0) {
    __shared__ char ldsA[32 * 512];  // 16 KB
    __shared__ char ldsB[32 * 512];  // 16 KB
    const int t = threadIdx.x;
    const int lane = t & 63;
    const int w = t >> 6;
    const long long row0 = (long long)blockIdx.x * 32;

    // stage x tile (fp32 -> fp16, swizzled); 32x64 float4, no bounds needed
    {
        const float4* A4 = reinterpret_cast<const float4*>(x + row0 * 256);
        for (int i = t; i < 2048; i += 256) {
            int r = i >> 6, c4 = i & 63;
            float4 v = A4[i];
            half4v hv;
            hv[0] = (_Float16)v.x; hv[1] = (_Float16)v.y;
            hv[2] = (_Float16)v.z; hv[3] = (_Float16)v.w;
            int bo = (r * 512 + c4 * 8) ^ ((r & 7) << 4);
            *reinterpret_cast<half4v*>(ldsA + bo) = hv;
        }
    }
    __syncthreads();

    gemm256_lds32(ldsA, ldsB, reinterpret_cast<const half8v*>(Wf1), b1, lane, w);  // h1 -> ldsB
    __syncthreads();
    gemm256_lds32(ldsB, ldsA, reinterpret_cast<const half8v*>(Wf2), b2, lane, w);  // h2 -> ldsA
    __syncthreads();

    // GEMM3: 32x256 @ 256x32; wave w: rows [16*(w>>1), +16), cols [16*(w&1), +16)
    const half8v* Wf38 = reinterpret_cast<const half8v*>(Wf3);
    const int rt = w >> 1, ct = w & 1;
    f32x4 acc = (f32x4)0.f;
#pragma unroll
    for (int kt = 0; kt < 8; kt++) {
        int row = rt * 16 + (lane & 15);
        int bo = (row * 512 + kt * 64 + ((lane >> 4) << 4)) ^ ((row & 7) << 4);
        half8v a = *reinterpret_cast<const half8v*>(ldsA + bo);
        half8v b = Wf38[(kt * 2 + ct) * 64 + lane];
        acc = __builtin_amdgcn_mfma_f32_16x16x32_f16(a, b, acc, 0, 0, 0);
    }
    {
        int colc = ct * 16 + (lane & 15);
        float bv = b3[colc];
#pragma unroll
        for (int r = 0; r < 4; r++) {
            long long row = row0 + rt * 16 + (lane >> 4) * 4 + r;
            float v = acc[r] + bv;
            h0[row * 32 + colc] = v;
            hs0[row * 32 + colc] = dinv[row] * v;
        }
    }
}

// ---------------- fused APPNP step (per-node gather, 4-way unrolled) ----------------

template<bool FINAL>
__global__ __launch_bounds__(256) void k_appnp(const int* __restrict__ begp,
                                               const int* __restrict__ endp,
                                               const int* __restrict__ col,
                                               const float* __restrict__ dinv,
                                               const float* __restrict__ hs,
                                               const float* __restrict__ h0,
                                               float* __restrict__ outp) {
    int node = blockIdx.x * 8 + (threadIdx.x >> 5);
    if (node >= NN) return;
    int c = threadIdx.x & 31;
    int e = begp[node];
    const int end = endp[node];
    float a0 = 0.f, a1 = 0.f, a2 = 0.f, a3 = 0.f;
    for (; e + 4 <= end; e += 4) {
        int s0 = col[e], s1 = col[e + 1], s2 = col[e + 2], s3 = col[e + 3];
        a0 += hs[(size_t)s0 * 32 + c];
        a1 += hs[(size_t)s1 * 32 + c];
        a2 += hs[(size_t)s2 * 32 + c];
        a3 += hs[(size_t)s3 * 32 + c];
    }
    for (; e < end; e++) a0 += hs[(size_t)col[e] * 32 + c];
    size_t off = (size_t)node * 32 + c;
    float dd = dinv[node];
    float hnew = 0.9f * dd * (((a0 + a1) + (a2 + a3)) + hs[off]) + 0.1f * h0[off];
    outp[off] = FINAL ? hnew : dd * hnew;
}

// ---------------- launch ----------------

extern "C" void kernel_launch(void* const* d_in, const int* in_sizes, int n_in,
                              void* d_out, int out_size, void* d_ws, size_t ws_size,
                              hipStream_t stream) {
    const float* x     = (const float*)d_in[0];
    const int*   ei    = (const int*)d_in[1];
    const float* W_in  = (const float*)d_in[2];
    const float* b_in  = (const float*)d_in[3];
    const float* W_h   = (const float*)d_in[4];
    const float* b_h   = (const float*)d_in[5];
    const float* W_out = (const float*)d_in[6];
    const float* b_out = (const float*)d_in[7];
    float* out = (float*)d_out;

    const int* srcv = ei;
    const int* dstv = ei + NE;

    char* ws = (char*)d_ws;
    float* h0      = (float*)ws;                                 // NN*32 f32
    float* hs0     = h0 + (size_t)NN * 32;                       // NN*32
    float* hs1     = hs0 + (size_t)NN * 32;                      // NN*32
    float* dinv    = hs1 + (size_t)NN * 32;                      // NN
    _Float16* Wf_in  = (_Float16*)(dinv + NN);                   // 256*256
    _Float16* Wf_h   = Wf_in + 256 * 256;                        // 256*256
    _Float16* Wf_out = Wf_h + 256 * 256;                         // 256*32
    int* histT = (int*)(Wf_out + 256 * 32);                      // NBUCK*NCHK
    int* cntb  = histT + (size_t)NBUCK * NCHK;                   // NBUCKP
    int* data  = cntb + NBUCKP;                                  // NBUCKP*CAP
    int* col   = data + (size_t)NBUCKP * CAP;                    // NBUCKP*CAP
    int* begp  = col + (size_t)NBUCKP * CAP;                     // NN
    int* endp  = begp + NN;                                      // NN

    // --- bucket partition + local counting sort -> CSR + dinv ---
    k_count<<<NCHK, 256, 0, stream>>>(dstv, histT);
    k_scanb<<<NBUCK, 256, 0, stream>>>(histT, cntb);
    k_part<<<NCHK, 256, 0, stream>>>(srcv, dstv, histT, data);
    k_sortb<<<NBUCK, 256, 0, stream>>>(data, cntb, col, begp, endp, dinv);

    // --- W fragments (one launch) ---
    k_wfrag_all<<<544, 256, 0, stream>>>(W_in, W_h, W_out, Wf_in, Wf_h, Wf_out);

    // --- fused MLP (x -> h0, hs0), 32-row tiles ---
    k_mlp<<<NN / 32, 256, 0, stream>>>(x, Wf_in, Wf_h, Wf_out, b_in, b_h, b_out,
                                       dinv, h0, hs0);

    // --- APPNP: K = 2 ---
    k_appnp<false><<<(NN + 7) / 8, 256, 0, stream>>>(begp, endp, col, dinv, hs0, h0, hs1);
    k_appnp<true ><<<(NN + 7) / 8, 256, 0, stream>>>(begp, endp, col, dinv, hs1, h0, out);
}